// Round 2
// baseline (1017.862 us; speedup 1.0000x reference)
//
#include <hip/hip_runtime.h>
#include <math.h>

#define HDIM 256
#define WDIM 512
#define BB 32
#define HW (HDIM*WDIM)

constexpr float PI_F = 3.14159265358979323846f;
constexpr float DEPTH_THRESH = 10.0f;
constexpr float BASELINE = 0.26f;
constexpr float ALPHA = 0.85f;
constexpr float LAMBDA_NORM = 0.05f;
constexpr float MMAP_COS_THRESH = 0.9f;
constexpr float EPS = 1e-6f;

__device__ __forceinline__ float attn_of_h(int h) {
  float theta = ((h + 0.5f) * (1.0f / HDIM) - 0.5f) * PI_F;
  float a = 1.0f - fabsf(theta) / (0.5f * PI_F);
  return fminf(fmaxf(a, 0.0f), 1.0f);
}

template <int N>
__device__ __forceinline__ void block_reduce_add(float (&v)[N], double* acc, int base) {
  #pragma unroll
  for (int off = 32; off; off >>= 1) {
    #pragma unroll
    for (int j = 0; j < N; j++) v[j] += __shfl_down(v[j], off);
  }
  __shared__ float sb[N * 4];
  int wid = threadIdx.x >> 6, lane = threadIdx.x & 63;
  if (lane == 0) {
    #pragma unroll
    for (int j = 0; j < N; j++) sb[j * 4 + wid] = v[j];
  }
  __syncthreads();
  if (threadIdx.x == 0) {
    #pragma unroll
    for (int j = 0; j < N; j++) {
      float s = sb[j * 4 + 0] + sb[j * 4 + 1] + sb[j * 4 + 2] + sb[j * 4 + 3];
      atomicAdd(&acc[base + j], (double)s);
    }
  }
}

// ---------------- Splat: vertical 2-tap forward warp, per-column in LDS ----------
__global__ __launch_bounds__(256) void splat_kernel(
    const float* __restrict__ rgb, const float* __restrict__ depth,
    float* __restrict__ outw) {
  __shared__ float aw[HDIM * 8], ar[HDIM * 8], ag[HDIM * 8], ab[HDIM * 8];
  int blk = blockIdx.x;
  int b = blk >> 6;            // W/8 = 64 column-groups per image
  int w0 = (blk & 63) << 3;
  int t = threadIdx.x;
  for (int i = t; i < HDIM * 8; i += 256) { aw[i] = 0.f; ar[i] = 0.f; ag[i] = 0.f; ab[i] = 0.f; }
  __syncthreads();
  const float* dep = depth + (size_t)b * HW;
  const float* rg  = rgb + (size_t)b * 3 * HW;
  #pragma unroll
  for (int it = 0; it < 8; ++it) {
    int idx = (it << 8) + t;
    int wl = idx & 7, h = idx >> 3;
    int g = h * WDIM + w0 + wl;
    float d = dep[g];
    float theta = ((h + 0.5f) * (1.0f / HDIM) - 0.5f) * PI_F;
    float st = sinf(theta), ct = cosf(theta);
    float theta2 = atan2f(d * st - BASELINE, d * ct);
    float cv = (float)h + (theta2 - theta) * ((float)HDIM / PI_F);
    float v0f = floorf(cv);
    int v0 = (int)v0f;
    float dv = cv - v0f;
    if (d < DEPTH_THRESH) {
      float r = rg[g], gg = rg[HW + g], bl = rg[2 * HW + g];
      if (v0 >= 0 && v0 < HDIM) {
        float wgt = 1.f - dv; int a = v0 * 8 + wl;
        atomicAdd(&aw[a], wgt); atomicAdd(&ar[a], r * wgt);
        atomicAdd(&ag[a], gg * wgt); atomicAdd(&ab[a], bl * wgt);
      }
      int v1 = v0 + 1;
      if (v1 >= 0 && v1 < HDIM) {
        float wgt = dv; int a = v1 * 8 + wl;
        atomicAdd(&aw[a], wgt); atomicAdd(&ar[a], r * wgt);
        atomicAdd(&ag[a], gg * wgt); atomicAdd(&ab[a], bl * wgt);
      }
    }
  }
  __syncthreads();
  for (int i = t; i < HDIM * 8; i += 256) {
    int h = i >> 3, wl = i & 7;
    float inv = 1.f / fmaxf(aw[i], EPS);
    size_t g = (size_t)b * 3 * HW + h * WDIM + w0 + wl;
    outw[g] = ar[i] * inv;
    outw[g + HW] = ag[i] * inv;
    outw[g + 2 * HW] = ab[i] * inv;
  }
}

// ---------------- Photo loss: separable 7x7 Gaussian SSIM + L1, tiled ----------
__global__ __launch_bounds__(256) void photo_kernel(
    const float* __restrict__ xw, const float* __restrict__ yr,
    const float* __restrict__ up_depth, double* __restrict__ acc) {
  __shared__ float xs[38 * 40];
  __shared__ float ys[38 * 40];
  __shared__ float rxs[1216], rys[1216], rxxs[1216], ryys[1216], rxys[1216];

  int bt = blockIdx.x;
  int b = bt >> 7;             // 128 tiles (8x16) per image
  int rem = bt & 127;
  int h0 = (rem >> 4) << 5;
  int w0 = (rem & 15) << 5;
  int t = threadIdx.x;

  float G[7];
  {
    float s = 0.f;
    #pragma unroll
    for (int i = 0; i < 7; i++) { float a = (float)(i - 3); G[i] = expf(-a * a / 4.5f); s += G[i]; }
    #pragma unroll
    for (int i = 0; i < 7; i++) G[i] /= s;
  }

  float dssim_a[4] = {0.f, 0.f, 0.f, 0.f};
  float l1_a[4] = {0.f, 0.f, 0.f, 0.f};
  const float C1 = 1e-4f, C2 = 9e-4f;

  for (int c = 0; c < 3; ++c) {
    const float* xp = xw + ((size_t)(b * 3 + c)) * HW;
    const float* yp = yr + ((size_t)(b * 3 + c)) * HW;
    __syncthreads();
    for (int i = t; i < 38 * 38; i += 256) {
      int r = i / 38, cc = i % 38;
      int gh = h0 - 3 + r, gw = w0 - 3 + cc;
      bool in = (gh >= 0) && (gh < HDIM) && (gw >= 0) && (gw < WDIM);
      float xv = in ? xp[gh * WDIM + gw] : 0.f;
      float yv = in ? yp[gh * WDIM + gw] : 0.f;
      xs[r * 40 + cc] = xv; ys[r * 40 + cc] = yv;
    }
    __syncthreads();
    for (int i = t; i < 1216; i += 256) {
      int r = i >> 5, cc = i & 31;
      const float* xrow = xs + r * 40 + cc;
      const float* yrow = ys + r * 40 + cc;
      float sx = 0.f, sy = 0.f, sxx = 0.f, syy = 0.f, sxy = 0.f;
      #pragma unroll
      for (int k = 0; k < 7; k++) {
        float gk = G[k]; float xv = xrow[k], yv = yrow[k];
        sx += gk * xv; sy += gk * yv;
        sxx += gk * xv * xv; syy += gk * yv * yv; sxy += gk * xv * yv;
      }
      rxs[i] = sx; rys[i] = sy; rxxs[i] = sxx; ryys[i] = syy; rxys[i] = sxy;
    }
    __syncthreads();
    #pragma unroll
    for (int q = 0; q < 4; q++) {
      int o = t + (q << 8);
      int oh = o >> 5, ow = o & 31;
      float mx = 0.f, my = 0.f, cxx = 0.f, cyy = 0.f, cxy = 0.f;
      #pragma unroll
      for (int k = 0; k < 7; k++) {
        float gk = G[k]; int ro = (oh + k) * 32 + ow;
        mx += gk * rxs[ro]; my += gk * rys[ro];
        cxx += gk * rxxs[ro]; cyy += gk * ryys[ro]; cxy += gk * rxys[ro];
      }
      float sxx = cxx - mx * mx, syy = cyy - my * my, sxy = cxy - mx * my;
      float ssim = ((2.f * mx * my + C1) * (2.f * sxy + C2)) /
                   ((mx * mx + my * my + C1) * (sxx + syy + C2));
      dssim_a[q] += (1.f - ssim) * 0.5f;
      l1_a[q] += fabsf(xs[(oh + 3) * 40 + ow + 3] - ys[(oh + 3) * 40 + ow + 3]);
    }
  }

  float sums[2] = {0.f, 0.f};
  #pragma unroll
  for (int q = 0; q < 4; q++) {
    int o = t + (q << 8);
    int oh = o >> 5, ow = o & 31;
    int h = h0 + oh, w = w0 + ow;
    float pl = ALPHA * (dssim_a[q] * (1.f / 3.f)) + (1.f - ALPHA) * (l1_a[q] * (1.f / 3.f));
    float cut = (up_depth[(size_t)b * HW + h * WDIM + w] < DEPTH_THRESH) ? 1.f : 0.f;
    float wm = cut * attn_of_h(h);
    sums[0] += pl * wm; sums[1] += wm;
  }
  block_reduce_add<2>(sums, acc, 0);
}

// ---------------- Smooth + normal losses ----------
__global__ __launch_bounds__(256) void smoothnorm_kernel(
    const float* __restrict__ rgb, const float* __restrict__ depth,
    const float* __restrict__ up_depth, const float* __restrict__ vps,
    double* __restrict__ acc) {
  __shared__ float sT[HDIM], cT[HDIM], sP[WDIM], cP[WDIM];
  int t = threadIdx.x;
  if (t < HDIM) {
    float th = ((t + 0.5f) * (1.0f / HDIM) - 0.5f) * PI_F;
    sT[t] = sinf(th); cT[t] = cosf(th);
  }
  for (int i = t; i < WDIM; i += 256) {
    float ph = ((i + 0.5f) * (1.0f / WDIM) - 0.5f) * 2.0f * PI_F;
    sP[i] = sinf(ph); cP[i] = cosf(ph);
  }
  __syncthreads();

  size_t gid = (size_t)blockIdx.x * 256 + t;
  int b = (int)(gid >> 17);
  int hw = (int)(gid & (HW - 1));
  int h = hw >> 9, w = hw & (WDIM - 1);

  const float* dep = depth + (size_t)b * HW;
  const float* rg  = rgb + (size_t)b * 3 * HW;
  float d00 = dep[hw];

  float su = 0.f, gu = 0.f;
  if (w < WDIM - 1) {
    float d01 = dep[hw + 1];
    float ax = d01 * cT[h] * cP[w + 1] - d00 * cT[h] * cP[w];
    float ay = (d01 - d00) * sT[h];
    float az = d01 * cT[h] * sP[w + 1] - d00 * cT[h] * sP[w];
    su = fabsf(ax) + fabsf(ay) + fabsf(az);
    gu = fabsf(rg[hw + 1] - rg[hw]) + fabsf(rg[HW + hw + 1] - rg[HW + hw]) +
         fabsf(rg[2 * HW + hw + 1] - rg[2 * HW + hw]);
  }
  float sv = 0.f, gv = 0.f;
  if (h < HDIM - 1) {
    float d10 = dep[hw + WDIM];
    float ax = d10 * cT[h + 1] * cP[w] - d00 * cT[h] * cP[w];
    float ay = d10 * sT[h + 1] - d00 * sT[h];
    float az = d10 * cT[h + 1] * sP[w] - d00 * cT[h] * sP[w];
    sv = fabsf(ax) + fabsf(ay) + fabsf(az);
    gv = fabsf(rg[hw + WDIM] - rg[hw]) + fabsf(rg[HW + hw + WDIM] - rg[HW + hw]) +
         fabsf(rg[2 * HW + hw + WDIM] - rg[2 * HW + hw]);
  }
  float cut = (up_depth[(size_t)b * HW + hw] < DEPTH_THRESH) ? 1.f : 0.f;
  float wsm = (1.f - attn_of_h(h)) * cut;
  float smooth_c = (su * expf(-gu) + sv * expf(-gv)) * wsm;

  // normals (roll +/-3 with wrap on both axes)
  int wp = (w + 3) & (WDIM - 1), wmi = (w - 3) & (WDIM - 1);
  int hp = (h + 3) & (HDIM - 1), hm = (h - 3) & (HDIM - 1);
  float dwp = dep[h * WDIM + wp], dwm = dep[h * WDIM + wmi];
  float dhp = dep[hp * WDIM + w], dhm = dep[hm * WDIM + w];

  float pux = dwp * cT[h] * cP[wp] - dwm * cT[h] * cP[wmi];
  float puy = (dwp - dwm) * sT[h];
  float puz = dwp * cT[h] * sP[wp] - dwm * cT[h] * sP[wmi];
  float pvx = dhp * cT[hp] * cP[w] - dhm * cT[hm] * cP[w];
  float pvy = dhp * sT[hp] - dhm * sT[hm];
  float pvz = dhp * cT[hp] * sP[w] - dhm * cT[hm] * sP[w];
  // n = cross(dpv, dpu)
  float nx = pvy * puz - pvz * puy;
  float ny = pvz * pux - pvx * puz;
  float nz = pvx * puy - pvy * pux;
  float nn = sqrtf(nx * nx + ny * ny + nz * nz);
  float invn = 1.f / (nn + EPS);
  float px = nx * invn, py = ny * invn, pz = nz * invn;

  const float* vp = vps + b * 9;
  float s[3]; float an[3];
  #pragma unroll
  for (int k = 0; k < 3; k++) {
    float vx = vp[3 * k], vy = vp[3 * k + 1], vz = vp[3 * k + 2];
    float vn = sqrtf(vx * vx + vy * vy + vz * vz);
    float iv = 1.f / (vn + EPS);
    vx *= iv; vy *= iv; vz *= iv;
    an[k] = sqrtf(vx * vx + vy * vy + vz * vz);
    s[k] = vx * px + vy * py + vz * pz;
  }
  float best = s[0]; int kb = 0;
  if (s[1] > best) { best = s[1]; kb = 1; }
  if (s[2] > best) { best = s[2]; kb = 2; }
  if (-s[0] > best) { best = -s[0]; kb = 0; }
  if (-s[1] > best) { best = -s[1]; kb = 1; }
  if (-s[2] > best) { best = -s[2]; kb = 2; }
  float pnn = sqrtf(px * px + py * py + pz * pz);
  float cossim = best / (pnn * an[kb] + EPS);
  if (isnan(cossim)) cossim = 1.0f;
  float contrib = (best > MMAP_COS_THRESH) ? (1.f - cossim) : 0.f;

  float sums[3] = {smooth_c, cut, contrib};
  block_reduce_add<3>(sums, acc, 2);
}

__global__ void finalize_kernel(const double* __restrict__ acc, float* __restrict__ out) {
  if (threadIdx.x == 0 && blockIdx.x == 0) {
    double photo = acc[0] / (acc[1] + (double)EPS);
    double smooth = acc[2] / (acc[3] + (double)EPS);
    double norml = acc[4] / (double)((size_t)BB * HW);
    out[0] = (float)(photo + 0.1 * smooth + (double)LAMBDA_NORM * norml);
  }
}

extern "C" void kernel_launch(void* const* d_in, const int* in_sizes, int n_in,
                              void* d_out, int out_size, void* d_ws, size_t ws_size,
                              hipStream_t stream) {
  (void)in_sizes; (void)n_in; (void)out_size; (void)ws_size;
  const float* left_rgb = (const float*)d_in[0];
  const float* left_depth = (const float*)d_in[1];
  const float* up_depth = (const float*)d_in[2];
  const float* up_rgb = (const float*)d_in[3];
  const float* vps = (const float*)d_in[4];

  double* acc = (double*)d_ws;
  float* warp = (float*)((char*)d_ws + 256);

  hipMemsetAsync(d_ws, 0, 256, stream);
  splat_kernel<<<BB * (WDIM / 8), 256, 0, stream>>>(left_rgb, left_depth, warp);
  photo_kernel<<<BB * (HDIM / 32) * (WDIM / 32), 256, 0, stream>>>(warp, up_rgb, up_depth, acc);
  smoothnorm_kernel<<<(BB * HW) / 256, 256, 0, stream>>>(left_rgb, left_depth, up_depth, vps, acc);
  finalize_kernel<<<1, 64, 0, stream>>>(acc, (float*)d_out);
}

// Round 3
// 425.536 us; speedup vs baseline: 2.3920x; 2.3920x over previous
//
#include <hip/hip_runtime.h>
#include <math.h>

#define HDIM 256
#define WDIM 512
#define BB 32
#define HW (HDIM*WDIM)
#define NBIN 64   // accumulator replicas per variable (atomic de-contention)

constexpr float PI_F = 3.14159265358979323846f;
constexpr float DEPTH_THRESH = 10.0f;
constexpr float BASELINE = 0.26f;
constexpr float ALPHA = 0.85f;
constexpr float LAMBDA_NORM = 0.05f;
constexpr float MMAP_COS_THRESH = 0.9f;
constexpr float EPS = 1e-6f;

__device__ __forceinline__ float attn_of_h(int h) {
  float theta = ((h + 0.5f) * (1.0f / HDIM) - 0.5f) * PI_F;
  float a = 1.0f - fabsf(theta) / (0.5f * PI_F);
  return fminf(fmaxf(a, 0.0f), 1.0f);
}

// acc layout: acc[var * NBIN + bin], vars 0..4
template <int N>
__device__ __forceinline__ void block_reduce_add(float (&v)[N], double* acc, int base) {
  #pragma unroll
  for (int off = 32; off; off >>= 1) {
    #pragma unroll
    for (int j = 0; j < N; j++) v[j] += __shfl_down(v[j], off);
  }
  __shared__ float sb[N * 4];
  int wid = threadIdx.x >> 6, lane = threadIdx.x & 63;
  if (lane == 0) {
    #pragma unroll
    for (int j = 0; j < N; j++) sb[j * 4 + wid] = v[j];
  }
  __syncthreads();
  if (threadIdx.x == 0) {
    int bin = blockIdx.x & (NBIN - 1);
    #pragma unroll
    for (int j = 0; j < N; j++) {
      float s = sb[j * 4 + 0] + sb[j * 4 + 1] + sb[j * 4 + 2] + sb[j * 4 + 3];
      atomicAdd(&acc[(base + j) * NBIN + bin], (double)s);
    }
  }
}

// ---------------- Splat: vertical 2-tap forward warp, per-column in LDS ----------
__global__ __launch_bounds__(256) void splat_kernel(
    const float* __restrict__ rgb, const float* __restrict__ depth,
    float* __restrict__ outw) {
  __shared__ float aw[HDIM * 8], ar[HDIM * 8], ag[HDIM * 8], ab[HDIM * 8];
  int blk = blockIdx.x;
  int b = blk >> 6;            // W/8 = 64 column-groups per image
  int w0 = (blk & 63) << 3;
  int t = threadIdx.x;
  for (int i = t; i < HDIM * 8; i += 256) { aw[i] = 0.f; ar[i] = 0.f; ag[i] = 0.f; ab[i] = 0.f; }
  __syncthreads();
  const float* dep = depth + (size_t)b * HW;
  const float* rg  = rgb + (size_t)b * 3 * HW;
  #pragma unroll
  for (int it = 0; it < 8; ++it) {
    int idx = (it << 8) + t;
    int wl = idx & 7, h = idx >> 3;
    int g = h * WDIM + w0 + wl;
    float d = dep[g];
    float theta = ((h + 0.5f) * (1.0f / HDIM) - 0.5f) * PI_F;
    float st = sinf(theta), ct = cosf(theta);
    float theta2 = atan2f(d * st - BASELINE, d * ct);
    float cv = (float)h + (theta2 - theta) * ((float)HDIM / PI_F);
    float v0f = floorf(cv);
    int v0 = (int)v0f;
    float dv = cv - v0f;
    if (d < DEPTH_THRESH) {
      float r = rg[g], gg = rg[HW + g], bl = rg[2 * HW + g];
      if (v0 >= 0 && v0 < HDIM) {
        float wgt = 1.f - dv; int a = v0 * 8 + wl;
        atomicAdd(&aw[a], wgt); atomicAdd(&ar[a], r * wgt);
        atomicAdd(&ag[a], gg * wgt); atomicAdd(&ab[a], bl * wgt);
      }
      int v1 = v0 + 1;
      if (v1 >= 0 && v1 < HDIM) {
        float wgt = dv; int a = v1 * 8 + wl;
        atomicAdd(&aw[a], wgt); atomicAdd(&ar[a], r * wgt);
        atomicAdd(&ag[a], gg * wgt); atomicAdd(&ab[a], bl * wgt);
      }
    }
  }
  __syncthreads();
  for (int i = t; i < HDIM * 8; i += 256) {
    int h = i >> 3, wl = i & 7;
    float inv = 1.f / fmaxf(aw[i], EPS);
    size_t g = (size_t)b * 3 * HW + h * WDIM + w0 + wl;
    outw[g] = ar[i] * inv;
    outw[g + HW] = ag[i] * inv;
    outw[g + 2 * HW] = ab[i] * inv;
  }
}

// ---------------- Photo loss: separable 7x7 Gaussian SSIM + L1, tiled ----------
__global__ __launch_bounds__(256) void photo_kernel(
    const float* __restrict__ xw, const float* __restrict__ yr,
    const float* __restrict__ up_depth, double* __restrict__ acc) {
  __shared__ float xs[38 * 40];
  __shared__ float ys[38 * 40];
  __shared__ float rxs[1216], rys[1216], rxxs[1216], ryys[1216], rxys[1216];

  int bt = blockIdx.x;
  int b = bt >> 7;             // 128 tiles (8x16) per image
  int rem = bt & 127;
  int h0 = (rem >> 4) << 5;
  int w0 = (rem & 15) << 5;
  int t = threadIdx.x;

  float G[7];
  {
    float s = 0.f;
    #pragma unroll
    for (int i = 0; i < 7; i++) { float a = (float)(i - 3); G[i] = expf(-a * a / 4.5f); s += G[i]; }
    #pragma unroll
    for (int i = 0; i < 7; i++) G[i] /= s;
  }

  float dssim_a[4] = {0.f, 0.f, 0.f, 0.f};
  float l1_a[4] = {0.f, 0.f, 0.f, 0.f};
  const float C1 = 1e-4f, C2 = 9e-4f;

  for (int c = 0; c < 3; ++c) {
    const float* xp = xw + ((size_t)(b * 3 + c)) * HW;
    const float* yp = yr + ((size_t)(b * 3 + c)) * HW;
    __syncthreads();
    for (int i = t; i < 38 * 38; i += 256) {
      int r = i / 38, cc = i % 38;
      int gh = h0 - 3 + r, gw = w0 - 3 + cc;
      bool in = (gh >= 0) && (gh < HDIM) && (gw >= 0) && (gw < WDIM);
      float xv = in ? xp[gh * WDIM + gw] : 0.f;
      float yv = in ? yp[gh * WDIM + gw] : 0.f;
      xs[r * 40 + cc] = xv; ys[r * 40 + cc] = yv;
    }
    __syncthreads();
    for (int i = t; i < 1216; i += 256) {
      int r = i >> 5, cc = i & 31;
      const float* xrow = xs + r * 40 + cc;
      const float* yrow = ys + r * 40 + cc;
      float sx = 0.f, sy = 0.f, sxx = 0.f, syy = 0.f, sxy = 0.f;
      #pragma unroll
      for (int k = 0; k < 7; k++) {
        float gk = G[k]; float xv = xrow[k], yv = yrow[k];
        sx += gk * xv; sy += gk * yv;
        sxx += gk * xv * xv; syy += gk * yv * yv; sxy += gk * xv * yv;
      }
      rxs[i] = sx; rys[i] = sy; rxxs[i] = sxx; ryys[i] = syy; rxys[i] = sxy;
    }
    __syncthreads();
    #pragma unroll
    for (int q = 0; q < 4; q++) {
      int o = t + (q << 8);
      int oh = o >> 5, ow = o & 31;
      float mx = 0.f, my = 0.f, cxx = 0.f, cyy = 0.f, cxy = 0.f;
      #pragma unroll
      for (int k = 0; k < 7; k++) {
        float gk = G[k]; int ro = (oh + k) * 32 + ow;
        mx += gk * rxs[ro]; my += gk * rys[ro];
        cxx += gk * rxxs[ro]; cyy += gk * ryys[ro]; cxy += gk * rxys[ro];
      }
      float sxx = cxx - mx * mx, syy = cyy - my * my, sxy = cxy - mx * my;
      float ssim = ((2.f * mx * my + C1) * (2.f * sxy + C2)) /
                   ((mx * mx + my * my + C1) * (sxx + syy + C2));
      dssim_a[q] += (1.f - ssim) * 0.5f;
      l1_a[q] += fabsf(xs[(oh + 3) * 40 + ow + 3] - ys[(oh + 3) * 40 + ow + 3]);
    }
  }

  float sums[2] = {0.f, 0.f};
  #pragma unroll
  for (int q = 0; q < 4; q++) {
    int o = t + (q << 8);
    int oh = o >> 5, ow = o & 31;
    int h = h0 + oh, w = w0 + ow;
    float pl = ALPHA * (dssim_a[q] * (1.f / 3.f)) + (1.f - ALPHA) * (l1_a[q] * (1.f / 3.f));
    float cut = (up_depth[(size_t)b * HW + h * WDIM + w] < DEPTH_THRESH) ? 1.f : 0.f;
    float wm = cut * attn_of_h(h);
    sums[0] += pl * wm; sums[1] += wm;
  }
  block_reduce_add<2>(sums, acc, 0);
}

// ---------------- Smooth + normal losses (grid-stride: 4 px/thread) ----------
__global__ __launch_bounds__(256) void smoothnorm_kernel(
    const float* __restrict__ rgb, const float* __restrict__ depth,
    const float* __restrict__ up_depth, const float* __restrict__ vps,
    double* __restrict__ acc) {
  __shared__ float sT[HDIM], cT[HDIM], sP[WDIM], cP[WDIM];
  int t = threadIdx.x;
  if (t < HDIM) {
    float th = ((t + 0.5f) * (1.0f / HDIM) - 0.5f) * PI_F;
    sT[t] = sinf(th); cT[t] = cosf(th);
  }
  for (int i = t; i < WDIM; i += 256) {
    float ph = ((i + 0.5f) * (1.0f / WDIM) - 0.5f) * 2.0f * PI_F;
    sP[i] = sinf(ph); cP[i] = cosf(ph);
  }
  __syncthreads();

  int b = blockIdx.x >> 7;                     // 128 blocks per image
  int seg = (blockIdx.x & 127) << 10;          // 1024 px per block
  const float* dep = depth + (size_t)b * HW;
  const float* rg  = rgb + (size_t)b * 3 * HW;

  // vps normalization: uniform per image, compute once per thread (cheap)
  const float* vp = vps + b * 9;
  float vnx[3], vny[3], vnz[3], an[3];
  #pragma unroll
  for (int k = 0; k < 3; k++) {
    float vx = vp[3 * k], vy = vp[3 * k + 1], vz = vp[3 * k + 2];
    float vn = sqrtf(vx * vx + vy * vy + vz * vz);
    float iv = 1.f / (vn + EPS);
    vnx[k] = vx * iv; vny[k] = vy * iv; vnz[k] = vz * iv;
    an[k] = sqrtf(vnx[k] * vnx[k] + vny[k] * vny[k] + vnz[k] * vnz[k]);
  }

  float sums[3] = {0.f, 0.f, 0.f};

  #pragma unroll
  for (int p = 0; p < 4; ++p) {
    int hw = seg + (p << 8) + t;
    int h = hw >> 9, w = hw & (WDIM - 1);
    float d00 = dep[hw];

    float su = 0.f, gu = 0.f;
    if (w < WDIM - 1) {
      float d01 = dep[hw + 1];
      float ax = d01 * cT[h] * cP[w + 1] - d00 * cT[h] * cP[w];
      float ay = (d01 - d00) * sT[h];
      float az = d01 * cT[h] * sP[w + 1] - d00 * cT[h] * sP[w];
      su = fabsf(ax) + fabsf(ay) + fabsf(az);
      gu = fabsf(rg[hw + 1] - rg[hw]) + fabsf(rg[HW + hw + 1] - rg[HW + hw]) +
           fabsf(rg[2 * HW + hw + 1] - rg[2 * HW + hw]);
    }
    float sv = 0.f, gv = 0.f;
    if (h < HDIM - 1) {
      float d10 = dep[hw + WDIM];
      float ax = d10 * cT[h + 1] * cP[w] - d00 * cT[h] * cP[w];
      float ay = d10 * sT[h + 1] - d00 * sT[h];
      float az = d10 * cT[h + 1] * sP[w] - d00 * cT[h] * sP[w];
      sv = fabsf(ax) + fabsf(ay) + fabsf(az);
      gv = fabsf(rg[hw + WDIM] - rg[hw]) + fabsf(rg[HW + hw + WDIM] - rg[HW + hw]) +
           fabsf(rg[2 * HW + hw + WDIM] - rg[2 * HW + hw]);
    }
    float cut = (up_depth[(size_t)b * HW + hw] < DEPTH_THRESH) ? 1.f : 0.f;
    float wsm = (1.f - attn_of_h(h)) * cut;
    float smooth_c = (su * expf(-gu) + sv * expf(-gv)) * wsm;

    // normals (roll +/-3 with wrap on both axes)
    int wp = (w + 3) & (WDIM - 1), wmi = (w - 3) & (WDIM - 1);
    int hp = (h + 3) & (HDIM - 1), hm = (h - 3) & (HDIM - 1);
    float dwp = dep[h * WDIM + wp], dwm = dep[h * WDIM + wmi];
    float dhp = dep[hp * WDIM + w], dhm = dep[hm * WDIM + w];

    float pux = dwp * cT[h] * cP[wp] - dwm * cT[h] * cP[wmi];
    float puy = (dwp - dwm) * sT[h];
    float puz = dwp * cT[h] * sP[wp] - dwm * cT[h] * sP[wmi];
    float pvx = dhp * cT[hp] * cP[w] - dhm * cT[hm] * cP[w];
    float pvy = dhp * sT[hp] - dhm * sT[hm];
    float pvz = dhp * cT[hp] * sP[w] - dhm * cT[hm] * sP[w];
    // n = cross(dpv, dpu)
    float nx = pvy * puz - pvz * puy;
    float ny = pvz * pux - pvx * puz;
    float nz = pvx * puy - pvy * pux;
    float nn = sqrtf(nx * nx + ny * ny + nz * nz);
    float invn = 1.f / (nn + EPS);
    float px = nx * invn, py = ny * invn, pz = nz * invn;

    float s0 = vnx[0] * px + vny[0] * py + vnz[0] * pz;
    float s1 = vnx[1] * px + vny[1] * py + vnz[1] * pz;
    float s2 = vnx[2] * px + vny[2] * py + vnz[2] * pz;
    float best = s0; int kb = 0;
    if (s1 > best) { best = s1; kb = 1; }
    if (s2 > best) { best = s2; kb = 2; }
    if (-s0 > best) { best = -s0; kb = 0; }
    if (-s1 > best) { best = -s1; kb = 1; }
    if (-s2 > best) { best = -s2; kb = 2; }
    float pnn = sqrtf(px * px + py * py + pz * pz);
    float cossim = best / (pnn * an[kb] + EPS);
    if (isnan(cossim)) cossim = 1.0f;
    float contrib = (best > MMAP_COS_THRESH) ? (1.f - cossim) : 0.f;

    sums[0] += smooth_c; sums[1] += cut; sums[2] += contrib;
  }
  block_reduce_add<3>(sums, acc, 2);
}

__global__ void finalize_kernel(const double* __restrict__ acc, float* __restrict__ out) {
  if (threadIdx.x == 0 && blockIdx.x == 0) {
    double a[5];
    #pragma unroll
    for (int v = 0; v < 5; v++) {
      double s = 0.0;
      for (int i = 0; i < NBIN; i++) s += acc[v * NBIN + i];
      a[v] = s;
    }
    double photo = a[0] / (a[1] + (double)EPS);
    double smooth = a[2] / (a[3] + (double)EPS);
    double norml = a[4] / (double)((size_t)BB * HW);
    out[0] = (float)(photo + 0.1 * smooth + (double)LAMBDA_NORM * norml);
  }
}

extern "C" void kernel_launch(void* const* d_in, const int* in_sizes, int n_in,
                              void* d_out, int out_size, void* d_ws, size_t ws_size,
                              hipStream_t stream) {
  (void)in_sizes; (void)n_in; (void)out_size; (void)ws_size;
  const float* left_rgb = (const float*)d_in[0];
  const float* left_depth = (const float*)d_in[1];
  const float* up_depth = (const float*)d_in[2];
  const float* up_rgb = (const float*)d_in[3];
  const float* vps = (const float*)d_in[4];

  double* acc = (double*)d_ws;               // 5 vars x NBIN doubles = 2560 B
  float* warp = (float*)((char*)d_ws + 4096);

  hipMemsetAsync(d_ws, 0, 5 * NBIN * sizeof(double), stream);
  splat_kernel<<<BB * (WDIM / 8), 256, 0, stream>>>(left_rgb, left_depth, warp);
  photo_kernel<<<BB * (HDIM / 32) * (WDIM / 32), 256, 0, stream>>>(warp, up_rgb, up_depth, acc);
  smoothnorm_kernel<<<BB * 128, 256, 0, stream>>>(left_rgb, left_depth, up_depth, vps, acc);
  finalize_kernel<<<1, 64, 0, stream>>>(acc, (float*)d_out);
}